// Round 16
// baseline (356.998 us; speedup 1.0000x reference)
//
#include <hip/hip_runtime.h>
#include <math.h>

#define NB 8
#define NN 1024
#define NH 256
#define NL 3

typedef unsigned short u16;
typedef __bf16 bf16x8 __attribute__((ext_vector_type(8)));
typedef _Float16 f16x8 __attribute__((ext_vector_type(8)));
typedef float f32x4 __attribute__((ext_vector_type(4)));

constexpr int EPI_BIAS_RELU = 2, EPI_EDIST = 5, EPI_QKV = 6;

__device__ __forceinline__ unsigned bf16rne(float f) {
    unsigned u = __float_as_uint(f);
    return (u + 0x7fffu + ((u >> 16) & 1u)) >> 16;
}
__device__ __forceinline__ unsigned bfpair(float a, float b) {
    return bf16rne(a) | (bf16rne(b) << 16);
}
__device__ __forceinline__ float bf2f(u16 h) {
    unsigned u = ((unsigned)h) << 16;
    return __uint_as_float(u);
}

__device__ __forceinline__ float blockSum256(float v) {
    __shared__ float sm[4];
    #pragma unroll
    for (int o = 32; o; o >>= 1) v += __shfl_down(v, o, 64);
    int lane = threadIdx.x & 63, wid = threadIdx.x >> 6;
    if (lane == 0) sm[wid] = v;
    __syncthreads();
    if (threadIdx.x == 0) sm[0] = sm[0] + sm[1] + sm[2] + sm[3];
    __syncthreads();
    float r = sm[0];
    __syncthreads();
    return r;
}

// ====== MFMA GEMM: MTx128 tile (MT=128 or 64), BK=64, 256 thr, 4 waves ======
template <int EPI, int DT, bool OBF, int SWZ, int MT>
__global__ __launch_bounds__(256) void gemm_mfma(
    const u16* __restrict__ A, int lda, long sA,
    const u16* __restrict__ Bt, int ldb, long sB,
    void* __restrict__ C, int ldc, long sC,
    int K,
    const float* __restrict__ bias, long sBias,
    u16* __restrict__ vtout)
{
    constexpr int MF = MT / 32;
    constexpr int ASZ = MT * 8;
    __shared__ uint4 sm4[ASZ + 1024];
    const int tid = threadIdx.x;

    int bx = blockIdx.x, by = blockIdx.y, bz = blockIdx.z;
    bool trans = false;
    if (SWZ == 2) {
        int gx = gridDim.x;
        int T = gx * gridDim.y;
        int lid = bx + gx * by;
        int nl = (lid & 7) * (T >> 3) + (lid >> 3);
        bx = nl % gx; by = nl / gx;
    } else if (SWZ == 3) {
        int lid = bx + gridDim.x * bz;   // grid (72,1,8)
        bz = lid & 7;
        int idx = lid >> 3;
        int j = 0;
        while (idx >= 16 - 2 * j) { idx -= 16 - 2 * j; j++; }
        by = 2 * j + idx;
        bx = j;
        trans = (by >= 2 * bx + 2);
    }
    const int z = bz;
    const int row0 = by * MT, col0 = bx * 128;

    f32x4 acc[MF][4];
    #pragma unroll
    for (int m = 0; m < MF; m++)
        #pragma unroll
        for (int n = 0; n < 4; n++) acc[m][n] = (f32x4){0.f, 0.f, 0.f, 0.f};

    const int l = tid & 63, wid = tid >> 6;
    const int wr = wid >> 1, wc = wid & 1;
    const int lrow = l & 15, lgrp = l >> 4;

    for (int k0 = 0; k0 < K; k0 += 64) {
        if (MT == 128) {
            const int srow = tid >> 1, half = tid & 1, cb = half * 4, swz = srow & 7;
            const u16* Ap = A + (long)z * sA + (long)(row0 + srow) * lda + k0 + half * 32;
            uint4 a0 = *(const uint4*)(Ap + 0),  a1 = *(const uint4*)(Ap + 8);
            uint4 a2 = *(const uint4*)(Ap + 16), a3 = *(const uint4*)(Ap + 24);
            sm4[srow * 8 + ((cb + 0) ^ swz)] = a0;
            sm4[srow * 8 + ((cb + 1) ^ swz)] = a1;
            sm4[srow * 8 + ((cb + 2) ^ swz)] = a2;
            sm4[srow * 8 + ((cb + 3) ^ swz)] = a3;
        } else {
            const int arow = tid >> 2, aq = tid & 3, swz = arow & 7;
            const u16* Ap = A + (long)z * sA + (long)(row0 + arow) * lda + k0 + aq * 16;
            uint4 a0 = *(const uint4*)(Ap + 0), a1 = *(const uint4*)(Ap + 8);
            sm4[arow * 8 + ((aq * 2 + 0) ^ swz)] = a0;
            sm4[arow * 8 + ((aq * 2 + 1) ^ swz)] = a1;
        }
        {
            const int brow = tid >> 1, bq = tid & 1, cb = bq * 4, swz = brow & 7;
            const u16* Bp = Bt + (long)z * sB + (long)(col0 + brow) * ldb + k0 + bq * 32;
            uint4 b0 = *(const uint4*)(Bp + 0),  b1 = *(const uint4*)(Bp + 8);
            uint4 b2 = *(const uint4*)(Bp + 16), b3 = *(const uint4*)(Bp + 24);
            sm4[ASZ + brow * 8 + ((cb + 0) ^ swz)] = b0;
            sm4[ASZ + brow * 8 + ((cb + 1) ^ swz)] = b1;
            sm4[ASZ + brow * 8 + ((cb + 2) ^ swz)] = b2;
            sm4[ASZ + brow * 8 + ((cb + 3) ^ swz)] = b3;
        }
        __syncthreads();

        #pragma unroll
        for (int ks = 0; ks < 2; ks++) {
            int c = ks * 4 + lgrp;
            uint4 a[MF], b[4];
            #pragma unroll
            for (int m = 0; m < MF; m++) {
                int r = wr * (MT / 2) + m * 16 + lrow;
                a[m] = sm4[r * 8 + (c ^ (r & 7))];
            }
            #pragma unroll
            for (int n = 0; n < 4; n++) {
                int r = wc * 64 + n * 16 + lrow;
                b[n] = sm4[ASZ + r * 8 + (c ^ (r & 7))];
            }
            #pragma unroll
            for (int m = 0; m < MF; m++)
                #pragma unroll
                for (int n = 0; n < 4; n++) {
                    if (DT == 0)
                        acc[m][n] = __builtin_amdgcn_mfma_f32_16x16x32_bf16(
                            __builtin_bit_cast(bf16x8, a[m]), __builtin_bit_cast(bf16x8, b[n]), acc[m][n], 0, 0, 0);
                    else
                        acc[m][n] = __builtin_amdgcn_mfma_f32_16x16x32_f16(
                            __builtin_bit_cast(f16x8, a[m]), __builtin_bit_cast(f16x8, b[n]), acc[m][n], 0, 0, 0);
                }
        }
        __syncthreads();
    }

    u16* Ts = (u16*)sm4;
    #pragma unroll
    for (int m = 0; m < MF; m++) {
        #pragma unroll
        for (int n = 0; n < 4; n++) {
            int rbase = row0 + wr * (MT / 2) + m * 16 + lgrp * 4;
            int cc = col0 + wc * 64 + n * 16 + lrow;
            float bv = 0.f;
            if (EPI == EPI_QKV || EPI == EPI_BIAS_RELU)
                bv = bias[cc];
            float vals[4];
            #pragma unroll
            for (int reg = 0; reg < 4; reg++) {
                long r = rbase + reg;
                float v = acc[m][n][reg];
                if (EPI == EPI_QKV) v += bv;
                else if (EPI == EPI_BIAS_RELU) v = fmaxf(v + bv, 0.f);
                else if (EPI == EPI_EDIST) {
                    const float* rnb = bias + (long)z * sBias;
                    float d2 = fmaxf(rnb[r] + rnb[cc] - 2.f * v, 0.f);
                    v = (r == cc) ? 1.f : expf(-sqrtf(d2));
                }
                vals[reg] = v;
                if (OBF) ((u16*)C)[(long)z * sC + r * ldc + cc] = (u16)bf16rne(v);
                else     ((float*)C)[(long)z * sC + r * ldc + cc] = v;
            }
            if (EPI == EPI_EDIST && SWZ == 3 && trans) {
                int cl = cc - col0, rl = rbase - row0;
                uint2 tv;
                tv.x = bfpair(vals[0], vals[1]);
                tv.y = bfpair(vals[2], vals[3]);
                *(uint2*)(Ts + cl * 68 + rl) = tv;
            }
            if (EPI == EPI_QKV && cc >= 512) {
                int b = rbase >> 10;
                uint2 tv;
                tv.x = bfpair(vals[0], vals[1]);
                tv.y = bfpair(vals[2], vals[3]);
                *(uint2*)&vtout[(long)b * NH * NN + (long)(cc - 512) * NN + (rbase & 1023)] = tv;
            }
        }
    }
    if (EPI == EPI_EDIST && SWZ == 3 && trans) {
        __syncthreads();
        int row = tid >> 1, half = tid & 1;
        const u16* src = Ts + row * 68 + half * 32;
        uint2 v0 = *(const uint2*)(src + 0),  v1 = *(const uint2*)(src + 4);
        uint2 v2 = *(const uint2*)(src + 8),  v3 = *(const uint2*)(src + 12);
        uint2 v4 = *(const uint2*)(src + 16), v5 = *(const uint2*)(src + 20);
        uint2 v6 = *(const uint2*)(src + 24), v7 = *(const uint2*)(src + 28);
        uint4* dst = (uint4*)((u16*)C + (long)z * sC + (long)(col0 + row) * ldc + row0 + half * 32);
        uint4 w0 = {v0.x, v0.y, v1.x, v1.y};
        uint4 w1 = {v2.x, v2.y, v3.x, v3.y};
        uint4 w2 = {v4.x, v4.y, v5.x, v5.y};
        uint4 w3 = {v6.x, v6.y, v7.x, v7.y};
        dst[0] = w0; dst[1] = w1; dst[2] = w2; dst[3] = w3;
    }
}

// ==== flash partial: KV-split half, KCHUNK=64, LDS ~76KB -> 2 blocks/CU ======
// grid (32,8,2): (b,q0) as before, z = kv-half. Writes UNNORMALIZED partial O
// (fp32) + partial rowsums. QK: 8 waves = 2 qm x 4 kf 16x16 tiles.
__global__ __launch_bounds__(512) void flash_part_k(
    const u16* __restrict__ qkv,
    const u16* __restrict__ vt,
    const u16* __restrict__ edist,
    float* __restrict__ po,     // [2][8][1024][256] fp32
    float* __restrict__ prs,    // [2][8][1024] fp32
    float scale)
{
    __shared__ uint4 Ks[64][32];          // 32 KB
    __shared__ uint4 Vts[256][8];         // 32 KB
    __shared__ __align__(16) u16 Es[32][72];
    __shared__ __align__(16) u16 Ps[32][72];
    __shared__ float rs[32][4];

    const int tid = threadIdx.x;
    const int l = tid & 63, w = tid >> 6;
    const int g = l >> 4, lr = l & 15;

    int lid = blockIdx.x + gridDim.x * blockIdx.y;
    const int b = lid & 7;
    const int q0 = (lid >> 3) * 32;
    const int kh = blockIdx.z;
    const int kv0 = kh * 512;

    const u16* qkvb = qkv + (long)b * NN * 768;
    const u16* vtb  = vt + (long)b * NH * NN;
    const u16* eb   = edist + (long)b * NN * NN;

    const int qm = w >> 2, kf = w & 3;

    // Q frag for this wave's qm only: rows q0+16*qm+lr
    uint4 qf[8];
    #pragma unroll
    for (int ks = 0; ks < 8; ks++)
        qf[ks] = *(const uint4*)(qkvb + (long)(q0 + 16 * qm + lr) * 768 + 32 * ks + 8 * g);

    f32x4 oacc[2][2];
    #pragma unroll
    for (int m = 0; m < 2; m++)
        #pragma unroll
        for (int nf = 0; nf < 2; nf++) oacc[m][nf] = (f32x4){0.f, 0.f, 0.f, 0.f};
    float rsum[4] = {0.f, 0.f, 0.f, 0.f};

    for (int it = 0; it < 8; ++it) {
        const int n0 = kv0 + it * 64;
        // stage K (64 keys x 256): 2048 chunks / 512 thr
        #pragma unroll
        for (int i = 0; i < 4; i++) {
            int idx = tid + 512 * i;
            int row = idx >> 5, ch = idx & 31;
            Ks[row][ch ^ (row & 7)] = *(const uint4*)(qkvb + (long)(n0 + row) * 768 + 256 + ch * 8);
        }
        // stage Vt (256 c x 64 keys): 2048 chunks
        #pragma unroll
        for (int i = 0; i < 4; i++) {
            int idx = tid + 512 * i;
            int c = idx >> 3, ch = idx & 7;
            Vts[c][ch ^ (c & 7)] = *(const uint4*)(vtb + (long)c * NN + n0 + ch * 8);
        }
        // stage E (32 q x 64 keys): 256 chunks
        if (tid < 256) {
            int r = tid >> 3, ch = tid & 7;
            *(uint4*)&Es[r][ch * 8] = *(const uint4*)(eb + (long)(q0 + r) * NN + n0 + ch * 8);
        }
        __syncthreads();

        // QK^T: wave (qm,kf) computes 16x16 tile (q rows 16qm.., keys 16kf..)
        f32x4 s = (f32x4){0.f, 0.f, 0.f, 0.f};
        const int krow = 16 * kf + lr;
        #pragma unroll
        for (int ks = 0; ks < 8; ks++) {
            bf16x8 kfrag = __builtin_bit_cast(bf16x8, Ks[krow][(4 * ks + g) ^ (krow & 7)]);
            s = __builtin_amdgcn_mfma_f32_16x16x32_bf16(__builtin_bit_cast(bf16x8, qf[ks]), kfrag, s, 0, 0, 0);
        }
        #pragma unroll
        for (int reg = 0; reg < 4; reg++) {
            int q = 16 * qm + 4 * g + reg;
            int kc = 16 * kf + lr;
            float p = expf(s[reg] * scale * bf2f(Es[q][kc]));
            rsum[reg] += p;
            Ps[q][kc] = (u16)bf16rne(p);
        }
        __syncthreads();

        // PV: wave owns O cols 32w..32w+31; A rows all 32 (m=0,1)
        #pragma unroll
        for (int ks = 0; ks < 2; ks++) {
            bf16x8 pa[2];
            #pragma unroll
            for (int m = 0; m < 2; m++)
                pa[m] = __builtin_bit_cast(bf16x8, *(const uint4*)&Ps[16 * m + lr][32 * ks + 8 * g]);
            #pragma unroll
            for (int nf = 0; nf < 2; nf++) {
                int c = 32 * w + 16 * nf + lr;
                bf16x8 vbf = __builtin_bit_cast(bf16x8, Vts[c][(4 * ks + g) ^ (c & 7)]);
                #pragma unroll
                for (int m = 0; m < 2; m++)
                    oacc[m][nf] = __builtin_amdgcn_mfma_f32_16x16x32_bf16(pa[m], vbf, oacc[m][nf], 0, 0, 0);
            }
        }
        __syncthreads();
    }

    // partial rowsum reduce over lr (keys within this wave's kf group)
    #pragma unroll
    for (int reg = 0; reg < 4; reg++) {
        float v = rsum[reg];
        v += __shfl_xor(v, 1); v += __shfl_xor(v, 2);
        v += __shfl_xor(v, 4); v += __shfl_xor(v, 8);
        rsum[reg] = v;
    }
    if (lr == 0) {
        #pragma unroll
        for (int reg = 0; reg < 4; reg++)
            rs[16 * qm + 4 * g + reg][kf] = rsum[reg];
    }
    __syncthreads();

    // write unnormalized partial O + partial rowsums
    const long pbase = ((long)(kh * 8 + b) * NN + q0) * NH;
    #pragma unroll
    for (int m = 0; m < 2; m++)
        #pragma unroll
        for (int nf = 0; nf < 2; nf++)
            #pragma unroll
            for (int reg = 0; reg < 4; reg++) {
                int q = 16 * m + 4 * g + reg;
                int c = 32 * w + 16 * nf + lr;
                po[pbase + (long)q * NH + c] = oacc[m][nf][reg];
            }
    if ((w & 3) == 0 && lr == 0) {
        #pragma unroll
        for (int reg = 0; reg < 4; reg++) {
            int q = 16 * (w >> 2) + 4 * g + reg;
            float tot = rs[q][0] + rs[q][1] + rs[q][2] + rs[q][3];
            prs[(long)kh * 8192 + b * 1024 + q0 + q] = tot;
        }
    }
}

// ==== combine: sum halves, normalize, ao GEMM + residual + LN1 ==============
// grid (32,8), 512 thr (8 waves). Same thread->element mapping as R10 tail.
__global__ __launch_bounds__(512) void combine_k(
    const float* __restrict__ po,
    const float* __restrict__ prs,
    const u16* __restrict__ aow,
    const float* __restrict__ aob,
    const float* __restrict__ hres,
    const float* __restrict__ g1,
    const float* __restrict__ b1,
    float* __restrict__ xb,
    u16* __restrict__ xbbf)
{
    __shared__ __align__(16) u16 Os[32 * 264];
    __shared__ float lnA[32][8];
    __shared__ float lnB[32][8];

    const int tid = threadIdx.x;
    const int l = tid & 63, w = tid >> 6;
    const int g = l >> 4, lr = l & 15;

    int lid = blockIdx.x + gridDim.x * blockIdx.y;
    const int b = lid & 7;
    const int q0 = (lid >> 3) * 32;

    const long HALF = (long)8 * NN * NH;

    // combined, normalized O -> Os bf16
    #pragma unroll
    for (int m = 0; m < 2; m++) {
        float inv[4];
        #pragma unroll
        for (int reg = 0; reg < 4; reg++) {
            int q = 16 * m + 4 * g + reg;
            float t = prs[b * 1024 + q0 + q] + prs[8192 + b * 1024 + q0 + q];
            inv[reg] = 1.f / t;
        }
        #pragma unroll
        for (int nf = 0; nf < 2; nf++) {
            int c = 32 * w + 16 * nf + lr;
            #pragma unroll
            for (int reg = 0; reg < 4; reg++) {
                int q = 16 * m + 4 * g + reg;
                long i0 = ((long)b * NN + q0 + q) * NH + c;
                float o = (po[i0] + po[HALF + i0]) * inv[reg];
                Os[q * 264 + c] = (u16)bf16rne(o);
            }
        }
    }
    __syncthreads();

    // ao GEMM: Os(32x256) @ aow(256j x 256c)^T
    f32x4 aacc[2][2];
    #pragma unroll
    for (int m = 0; m < 2; m++)
        #pragma unroll
        for (int nf = 0; nf < 2; nf++) aacc[m][nf] = (f32x4){0.f, 0.f, 0.f, 0.f};
    #pragma unroll
    for (int kc = 0; kc < 8; kc++) {
        bf16x8 pa[2], wb[2];
        #pragma unroll
        for (int m = 0; m < 2; m++)
            pa[m] = __builtin_bit_cast(bf16x8, *(const uint4*)&Os[(16 * m + lr) * 264 + kc * 32 + 8 * g]);
        #pragma unroll
        for (int nf = 0; nf < 2; nf++)
            wb[nf] = __builtin_bit_cast(bf16x8, *(const uint4*)(aow + (long)(32 * w + 16 * nf + lr) * 256 + kc * 32 + 8 * g));
        #pragma unroll
        for (int m = 0; m < 2; m++)
            #pragma unroll
            for (int nf = 0; nf < 2; nf++)
                aacc[m][nf] = __builtin_amdgcn_mfma_f32_16x16x32_bf16(pa[m], wb[nf], aacc[m][nf], 0, 0, 0);
    }

    int j0 = 32 * w + lr, j1 = 32 * w + 16 + lr;
    float aob0 = aob[j0], aob1 = aob[j1];
    float xv[2][2][4];
    #pragma unroll
    for (int m = 0; m < 2; m++)
        #pragma unroll
        for (int reg = 0; reg < 4; reg++) {
            int q = 16 * m + 4 * g + reg;
            long hr = ((long)b * NN + q0 + q) * NH;
            xv[m][0][reg] = aacc[m][0][reg] + aob0 + hres[hr + j0];
            xv[m][1][reg] = aacc[m][1][reg] + aob1 + hres[hr + j1];
        }

    #pragma unroll
    for (int m = 0; m < 2; m++)
        #pragma unroll
        for (int reg = 0; reg < 4; reg++) {
            float s = xv[m][0][reg] + xv[m][1][reg];
            float s2 = xv[m][0][reg] * xv[m][0][reg] + xv[m][1][reg] * xv[m][1][reg];
            s  += __shfl_xor(s, 1);  s  += __shfl_xor(s, 2);  s  += __shfl_xor(s, 4);  s  += __shfl_xor(s, 8);
            s2 += __shfl_xor(s2, 1); s2 += __shfl_xor(s2, 2); s2 += __shfl_xor(s2, 4); s2 += __shfl_xor(s2, 8);
            if (lr == 0) {
                int q = 16 * m + 4 * g + reg;
                lnA[q][w] = s;
                lnB[q][w] = s2;
            }
        }
    __syncthreads();

    float g1v0 = g1[j0], g1v1 = g1[j1], b1v0 = b1[j0], b1v1 = b1[j1];
    #pragma unroll
    for (int m = 0; m < 2; m++)
        #pragma unroll
        for (int reg = 0; reg < 4; reg++) {
            int q = 16 * m + 4 * g + reg;
            float S = 0.f, S2 = 0.f;
            #pragma unroll
            for (int j = 0; j < 8; j++) { S += lnA[q][j]; S2 += lnB[q][j]; }
            float mu = S * (1.f / NH);
            float var = S2 * (1.f / NH) - mu * mu;
            float rsd = rsqrtf(var + 1e-5f);
            long hr = ((long)b * NN + q0 + q) * NH;
            float o0 = (xv[m][0][reg] - mu) * rsd * g1v0 + b1v0;
            float o1 = (xv[m][1][reg] - mu) * rsd * g1v1 + b1v1;
            xb[hr + j0] = o0;
            xb[hr + j1] = o1;
            xbbf[hr + j0] = (u16)bf16rne(o0);
            xbbf[hr + j1] = (u16)bf16rne(o1);
        }
}

// ==== fused fc2 + bias + relu + residual + LayerNorm2 ========================
__global__ __launch_bounds__(256) void fc2ln_k(
    const u16* __restrict__ f1,
    const float* __restrict__ resid,
    const u16* __restrict__ w2,
    const float* __restrict__ b2,
    const float* __restrict__ g2,
    const float* __restrict__ bb2,
    float* __restrict__ hout,
    u16* __restrict__ hbf)
{
    __shared__ uint4 As[256];
    __shared__ uint4 Bs[2048];
    __shared__ float lnA[32][4], lnB[32][4];

    const int tid = threadIdx.x;
    const int l = tid & 63, w = tid >> 6;
    const int lrow = l & 15, lgrp = l >> 4;
    const long r0 = (long)blockIdx.x * 32;

    f32x4 acc[2][4];
    #pragma unroll
    for (int m = 0; m < 2; m++)
        #pragma unroll
        for (int n = 0; n < 4; n++) acc[m][n] = (f32x4){0.f, 0.f, 0.f, 0.f};

    for (int k0 = 0; k0 < 1024; k0 += 64) {
        {
            int row = tid >> 3, ch = tid & 7;
            As[row * 8 + (ch ^ (row & 7))] = *(const uint4*)(f1 + (r0 + row) * 1024 + k0 + ch * 8);
        }
        #pragma unroll
        for (int i = 0; i < 8; i++) {
            int idx = tid + 256 * i;
            int row = idx >> 3, ch = idx & 7;
            Bs[row * 8 + (ch ^ (row & 7))] = *(const uint4*)(w2 + (long)row * 1024 + k0 + ch * 8);
        }
        __syncthreads();
        #pragma unroll
        for (int ks = 0; ks < 2; ks++) {
            int c = ks * 4 + lgrp;
            uint4 a[2], b[4];
            #pragma unroll
            for (int m = 0; m < 2; m++) {
                int r = m * 16 + lrow;
                a[m] = As[r * 8 + (c ^ (r & 7))];
            }
            #pragma unroll
            for (int n = 0; n < 4; n++) {
                int r = 64 * w + n * 16 + lrow;
                b[n] = Bs[r * 8 + (c ^ (r & 7))];
            }
            #pragma unroll
            for (int m = 0; m < 2; m++)
                #pragma unroll
                for (int n = 0; n < 4; n++)
                    acc[m][n] = __builtin_amdgcn_mfma_f32_16x16x32_bf16(
                        __builtin_bit_cast(bf16x8, a[m]), __builtin_bit_cast(bf16x8, b[n]), acc[m][n], 0, 0, 0);
        }
        __syncthreads();
    }

    float xv[2][4][4];
    #pragma unroll
    for (int m = 0; m < 2; m++)
        #pragma unroll
        for (int n = 0; n < 4; n++) {
            int cc = 64 * w + 16 * n + lrow;
            float bv = b2[cc];
            #pragma unroll
            for (int reg = 0; reg < 4; reg++) {
                int rr = 16 * m + 4 * lgrp + reg;
                xv[m][n][reg] = fmaxf(acc[m][n][reg] + bv, 0.f) + resid[(r0 + rr) * 256 + cc];
            }
        }

    #pragma unroll
    for (int m = 0; m < 2; m++)
        #pragma unroll
        for (int reg = 0; reg < 4; reg++) {
            float s = 0.f, s2 = 0.f;
            #pragma unroll
            for (int n = 0; n < 4; n++) {
                s += xv[m][n][reg];
                s2 += xv[m][n][reg] * xv[m][n][reg];
            }
            s  += __shfl_xor(s, 1);  s  += __shfl_xor(s, 2);  s  += __shfl_xor(s, 4);  s  += __shfl_xor(s, 8);
            s2 += __shfl_xor(s2, 1); s2 += __shfl_xor(s2, 2); s2 += __shfl_xor(s2, 4); s2 += __shfl_xor(s2, 8);
            if (lrow == 0) {
                int rr = 16 * m + 4 * lgrp + reg;
                lnA[rr][w] = s;
                lnB[rr][w] = s2;
            }
        }
    __syncthreads();

    #pragma unroll
    for (int m = 0; m < 2; m++)
        #pragma unroll
        for (int reg = 0; reg < 4; reg++) {
            int rr = 16 * m + 4 * lgrp + reg;
            float S = lnA[rr][0] + lnA[rr][1] + lnA[rr][2] + lnA[rr][3];
            float S2 = lnB[rr][0] + lnB[rr][1] + lnB[rr][2] + lnB[rr][3];
            float mu = S * (1.f / NH);
            float var = S2 * (1.f / NH) - mu * mu;
            float rsd = rsqrtf(var + 1e-5f);
            #pragma unroll
            for (int n = 0; n < 4; n++) {
                int cc = 64 * w + 16 * n + lrow;
                float o = (xv[m][n][reg] - mu) * rsd * g2[cc] + bb2[cc];
                hout[(r0 + rr) * 256 + cc] = o;
                hbf[(r0 + rr) * 256 + cc] = (u16)bf16rne(o);
            }
        }
}

__global__ __launch_bounds__(256) void base_k(const int* __restrict__ t,
                                              const float* __restrict__ w_time,
                                              const float* __restrict__ b_time,
                                              const float* __restrict__ w_in,
                                              const float* __restrict__ b_in,
                                              float* __restrict__ base) {
    int b = blockIdx.x, j = threadIdx.x;
    __shared__ float te[256];
    float tf = (float)t[b] / 200.0f;
    te[j] = fmaxf(tf * w_time[j] + b_time[j], 0.f);
    __syncthreads();
    float acc = b_in[j];
    for (int k = 0; k < 256; k++) acc = fmaf(te[k], w_in[(3 + k) * 256 + j], acc);
    base[b * 256 + j] = acc;
}

__global__ __launch_bounds__(256) void hinit_k(const float* __restrict__ x,
                                               const float* __restrict__ w_in,
                                               const float* __restrict__ base,
                                               float* __restrict__ h,
                                               u16* __restrict__ hbf,
                                               float* __restrict__ h3) {
    long row = blockIdx.x;
    int b = (int)(row >> 10);
    int j = threadIdx.x;
    float x0 = x[row * 3 + 0], x1 = x[row * 3 + 1], x2 = x[row * 3 + 2];
    float v = base[b * 256 + j];
    v = fmaf(x0, w_in[j], v);
    v = fmaf(x1, w_in[256 + j], v);
    v = fmaf(x2, w_in[512 + j], v);
    v = fmaxf(v, 0.f);
    h[row * 256 + j] = v;
    hbf[row * 256 + j] = (u16)bf16rne(v);
    if (j < 3) h3[row * 3 + j] = v;
}

__global__ __launch_bounds__(256) void geo_k(const float* __restrict__ h3,
                                             u16* __restrict__ gf,
                                             float* __restrict__ rn) {
    int bi = blockIdx.x;
    int b = bi >> 10, i = bi & 1023;
    const float* hb = h3 + (long)b * NN * 3;
    float ax = hb[i * 3 + 0], ay = hb[i * 3 + 1], az = hb[i * 3 + 2];
    u16* grow = gf + (long)bi * 1024;
    float accs = 0.f;
    #pragma unroll
    for (int j0 = 0; j0 < NN; j0 += 256) {
        int j = j0 + threadIdx.x;
        float dx = hb[j * 3 + 0] - ax, dy = hb[j * 3 + 1] - ay, dz = hb[j * 3 + 2] - az;
        float d2 = dx * dx + dy * dy + dz * dz;
        float d = (d2 > 0.f) ? sqrtf(d2) : 0.f;
        _Float16 hf = (_Float16)d;
        float rep = (float)hf;
        grow[j] = __builtin_bit_cast(u16, hf);
        accs += rep * rep;
    }
    float tot = blockSum256(accs);
    if (threadIdx.x == 0) rn[bi] = tot;
}

__global__ __launch_bounds__(256) void wtrans_k(const float* __restrict__ qkv_w,
                                                const float* __restrict__ ao_w,
                                                const float* __restrict__ fc1_w,
                                                const float* __restrict__ fc2_w,
                                                u16* __restrict__ qkv_wt,
                                                u16* __restrict__ ao_wt,
                                                u16* __restrict__ fc1_wt,
                                                u16* __restrict__ fc2_wt) {
    int type = blockIdx.z, lyr = blockIdx.y;
    int R, Cc;
    const float* src;
    u16* dst;
    if (type == 0) { R = 256; Cc = 768;  src = qkv_w + (long)lyr * R * Cc; dst = qkv_wt + (long)lyr * R * Cc; }
    else if (type == 1) { R = 256; Cc = 256; src = ao_w + (long)lyr * R * Cc; dst = ao_wt + (long)lyr * R * Cc; }
    else if (type == 2) { R = 256; Cc = 1024; src = fc1_w + (long)lyr * R * Cc; dst = fc1_wt + (long)lyr * R * Cc; }
    else { R = 1024; Cc = 256; src = fc2_w + (long)lyr * R * Cc; dst = fc2_wt + (long)lyr * R * Cc; }
    int tC = Cc >> 5, tR = R >> 5;
    int tile = blockIdx.x;
    if (tile >= tC * tR) return;
    int c0 = (tile % tC) << 5, r0 = (tile / tC) << 5;
    __shared__ float tf[32][33];
    int tx = threadIdx.x & 31, ty = threadIdx.x >> 5;
    #pragma unroll
    for (int i = 0; i < 4; i++) {
        int r = ty + 8 * i;
        tf[r][tx] = src[(long)(r0 + r) * Cc + c0 + tx];
    }
    __syncthreads();
    #pragma unroll
    for (int i = 0; i < 4; i++) {
        int c = ty + 8 * i;
        dst[(long)(c0 + c) * R + r0 + tx] = (u16)bf16rne(tf[tx][c]);
    }
}

__global__ __launch_bounds__(256) void out_k(const float* __restrict__ h,
                                             const float* __restrict__ w_out,
                                             const float* __restrict__ b_out,
                                             float* __restrict__ out) {
    long row = blockIdx.x;
    int wid = threadIdx.x >> 6, lane = threadIdx.x & 63;
    if (wid < 3) {
        float acc = 0.f;
        for (int k = lane; k < 256; k += 64) acc = fmaf(h[row * 256 + k], w_out[k * 3 + wid], acc);
        #pragma unroll
        for (int o = 32; o; o >>= 1) acc += __shfl_down(acc, o, 64);
        if (lane == 0) out[row * 3 + wid] = acc + b_out[wid];
    }
}

extern "C" void kernel_launch(void* const* d_in, const int* in_sizes, int n_in,
                              void* d_out, int out_size, void* d_ws, size_t ws_size,
                              hipStream_t stream) {
    const float* x      = (const float*)d_in[0];
    const int*   t      = (const int*)  d_in[1];
    const float* w_time = (const float*)d_in[3];
    const float* b_time = (const float*)d_in[4];
    const float* w_in   = (const float*)d_in[5];
    const float* b_in   = (const float*)d_in[6];
    const float* w_out  = (const float*)d_in[7];
    const float* b_out  = (const float*)d_in[8];
    const float* qkv_w  = (const float*)d_in[9];
    const float* qkv_b  = (const float*)d_in[10];
    const float* ao_w   = (const float*)d_in[11];
    const float* ao_b   = (const float*)d_in[12];
    const float* fc1_w  = (const float*)d_in[13];
    const float* fc1_b  = (const float*)d_in[14];
    const float* fc2_w  = (const float*)d_in[15];
    const float* fc2_b  = (const float*)d_in[16];
    const float* ln1_g  = (const float*)d_in[17];
    const float* ln1_b  = (const float*)d_in[18];
    const float* ln2_g  = (const float*)d_in[19];
    const float* ln2_b  = (const float*)d_in[20];
    float* out = (float*)d_out;

    char* W = (char*)d_ws;
    float* h     = (float*)(W);                          // 8 MB
    float* xb    = (float*)(W + (8ul << 20));            // 8 MB
    u16*   hbf   = (u16*)  (W + (16ul << 20));           // 4 MB
    u16*   xbbf  = (u16*)  (W + (20ul << 20));           // 4 MB
    u16*   vt    = (u16*)  (W + (24ul << 20));           // 4 MB
    u16*   f1    = (u16*)  (W + (28ul << 20));           // 16 MB
    u16*   qkvb  = (u16*)  (W + (44ul << 20));           // 12 MB
    u16*   edist = (u16*)  (W + (56ul << 20));           // 16 MB
    u16*   gf    = (u16*)  (W + (72ul << 20));           // 16 MB (fp16 geo)
    u16*   wts   = (u16*)  (W + (88ul << 20));           // 4.5 MB
    u16* qkv_wt = wts;
    u16* ao_wt  = wts + 589824;
    u16* fc1_wt = wts + 786432;
    u16* fc2_wt = wts + 1572864;
    float* base = (float*)(W + (94ul << 20));
    float* rn   = base + 2048;
    float* h3   = rn + 8192;
    float* prs  = (float*)(W + (95ul << 20));            // 64 KB
    float* po   = (float*)(W + (96ul << 20));            // 16 MB

    const float scale = 1.0f / 16.0f;

    base_k<<<NB, 256, 0, stream>>>(t, w_time, b_time, w_in, b_in, base);
    hinit_k<<<NB * NN, 256, 0, stream>>>(x, w_in, base, h, hbf, h3);
    geo_k<<<NB * NN, 256, 0, stream>>>(h3, gf, rn);
    wtrans_k<<<dim3(256, NL, 4), 256, 0, stream>>>(qkv_w, ao_w, fc1_w, fc2_w,
                                                   qkv_wt, ao_wt, fc1_wt, fc2_wt);
    // edist: fp16 Gram, K=1024, symmetric 64-row triangular tiles (576 blocks)
    gemm_mfma<EPI_EDIST, 1, true, 3, 64><<<dim3(72, 1, 8), 256, 0, stream>>>(
        gf, 1024, (long)NN * 1024, gf, 1024, (long)NN * 1024,
        edist, NN, (long)NN * NN, 1024, rn, NN, nullptr);

    for (int l = 0; l < NL; ++l) {
        // qkv (bf16 out, MT=64 -> 768 blocks) + fused v-transpose into vt
        gemm_mfma<EPI_QKV, 0, true, 2, 64><<<dim3(6, 128, 1), 256, 0, stream>>>(
            hbf, NH, 0, qkv_wt + (long)l * 196608, NH, 0, qkvb, 768, 0,
            NH, qkv_b + l * 768, 0, vt);
        // flash partials (KV-split, 512 blocks, 2/CU)
        flash_part_k<<<dim3(32, 8, 2), 512, 0, stream>>>(
            qkvb, vt, edist, po, prs, scale);
        // combine + ao-proj + residual + LN1 -> xb / xbbf
        combine_k<<<dim3(32, 8), 512, 0, stream>>>(
            po, prs, ao_wt + (long)l * 65536, ao_b + l * NH,
            h, ln1_g + l * NH, ln1_b + l * NH, xb, xbbf);
        // f1 = relu(xb @ fc1_wt^T + b)  (bf16 out)
        gemm_mfma<EPI_BIAS_RELU, 0, true, 2, 128><<<dim3(8, 64, 1), 256, 0, stream>>>(
            xbbf, NH, 0, fc1_wt + (long)l * 262144, NH, 0, f1, 1024, 0,
            NH, fc1_b + l * 1024, 0, nullptr);
        // fused fc2 + bias + relu + residual + LN2 -> h / hbf
        fc2ln_k<<<256, 256, 0, stream>>>(
            f1, xb, fc2_wt + (long)l * 262144, fc2_b + l * NH,
            ln2_g + l * NH, ln2_b + l * NH, h, hbf);
    }
    out_k<<<NB * NN, 256, 0, stream>>>(h, w_out, b_out, out);
}

// Round 17
// 318.641 us; speedup vs baseline: 1.1204x; 1.1204x over previous
//
#include <hip/hip_runtime.h>
#include <math.h>

#define NB 8
#define NN 1024
#define NH 256
#define NL 3

typedef unsigned short u16;
typedef __bf16 bf16x8 __attribute__((ext_vector_type(8)));
typedef _Float16 f16x8 __attribute__((ext_vector_type(8)));
typedef float f32x4 __attribute__((ext_vector_type(4)));

constexpr int EPI_BIAS_RELU = 2, EPI_EDIST = 5, EPI_QKV = 6;

__device__ __forceinline__ unsigned bf16rne(float f) {
    unsigned u = __float_as_uint(f);
    return (u + 0x7fffu + ((u >> 16) & 1u)) >> 16;
}
__device__ __forceinline__ unsigned bfpair(float a, float b) {
    return bf16rne(a) | (bf16rne(b) << 16);
}
__device__ __forceinline__ float bf2f(u16 h) {
    unsigned u = ((unsigned)h) << 16;
    return __uint_as_float(u);
}

__device__ __forceinline__ float blockSum256(float v) {
    __shared__ float sm[4];
    #pragma unroll
    for (int o = 32; o; o >>= 1) v += __shfl_down(v, o, 64);
    int lane = threadIdx.x & 63, wid = threadIdx.x >> 6;
    if (lane == 0) sm[wid] = v;
    __syncthreads();
    if (threadIdx.x == 0) sm[0] = sm[0] + sm[1] + sm[2] + sm[3];
    __syncthreads();
    float r = sm[0];
    __syncthreads();
    return r;
}

// ====== MFMA GEMM: MTx128 tile (MT=128 or 64), BK=64, 256 thr, 4 waves ======
// C = A @ Bt^T. A: MxK row-major. Bt: NxK row-major. DT: 0=bf16, 1=fp16.
// SWZ: 2 chunked (z=1 grids, blocks%8==0), 3 triangular-symmetric batch-pinned.
template <int EPI, int DT, bool OBF, int SWZ, int MT>
__global__ __launch_bounds__(256) void gemm_mfma(
    const u16* __restrict__ A, int lda, long sA,
    const u16* __restrict__ Bt, int ldb, long sB,
    void* __restrict__ C, int ldc, long sC,
    int K,
    const float* __restrict__ bias, long sBias,
    u16* __restrict__ vtout)
{
    constexpr int MF = MT / 32;
    constexpr int ASZ = MT * 8;
    __shared__ uint4 sm4[ASZ + 1024];
    const int tid = threadIdx.x;

    int bx = blockIdx.x, by = blockIdx.y, bz = blockIdx.z;
    bool trans = false;
    if (SWZ == 2) {
        int gx = gridDim.x;
        int T = gx * gridDim.y;
        int lid = bx + gx * by;
        int nl = (lid & 7) * (T >> 3) + (lid >> 3);
        bx = nl % gx; by = nl / gx;
    } else if (SWZ == 3) {
        int lid = bx + gridDim.x * bz;   // grid (72,1,8)
        bz = lid & 7;
        int idx = lid >> 3;
        int j = 0;
        while (idx >= 16 - 2 * j) { idx -= 16 - 2 * j; j++; }
        by = 2 * j + idx;
        bx = j;
        trans = (by >= 2 * bx + 2);
    }
    const int z = bz;
    const int row0 = by * MT, col0 = bx * 128;

    f32x4 acc[MF][4];
    #pragma unroll
    for (int m = 0; m < MF; m++)
        #pragma unroll
        for (int n = 0; n < 4; n++) acc[m][n] = (f32x4){0.f, 0.f, 0.f, 0.f};

    const int l = tid & 63, wid = tid >> 6;
    const int wr = wid >> 1, wc = wid & 1;
    const int lrow = l & 15, lgrp = l >> 4;

    for (int k0 = 0; k0 < K; k0 += 64) {
        if (MT == 128) {
            const int srow = tid >> 1, half = tid & 1, cb = half * 4, swz = srow & 7;
            const u16* Ap = A + (long)z * sA + (long)(row0 + srow) * lda + k0 + half * 32;
            uint4 a0 = *(const uint4*)(Ap + 0),  a1 = *(const uint4*)(Ap + 8);
            uint4 a2 = *(const uint4*)(Ap + 16), a3 = *(const uint4*)(Ap + 24);
            sm4[srow * 8 + ((cb + 0) ^ swz)] = a0;
            sm4[srow * 8 + ((cb + 1) ^ swz)] = a1;
            sm4[srow * 8 + ((cb + 2) ^ swz)] = a2;
            sm4[srow * 8 + ((cb + 3) ^ swz)] = a3;
        } else {
            const int arow = tid >> 2, aq = tid & 3, swz = arow & 7;
            const u16* Ap = A + (long)z * sA + (long)(row0 + arow) * lda + k0 + aq * 16;
            uint4 a0 = *(const uint4*)(Ap + 0), a1 = *(const uint4*)(Ap + 8);
            sm4[arow * 8 + ((aq * 2 + 0) ^ swz)] = a0;
            sm4[arow * 8 + ((aq * 2 + 1) ^ swz)] = a1;
        }
        {
            const int brow = tid >> 1, bq = tid & 1, cb = bq * 4, swz = brow & 7;
            const u16* Bp = Bt + (long)z * sB + (long)(col0 + brow) * ldb + k0 + bq * 32;
            uint4 b0 = *(const uint4*)(Bp + 0),  b1 = *(const uint4*)(Bp + 8);
            uint4 b2 = *(const uint4*)(Bp + 16), b3 = *(const uint4*)(Bp + 24);
            sm4[ASZ + brow * 8 + ((cb + 0) ^ swz)] = b0;
            sm4[ASZ + brow * 8 + ((cb + 1) ^ swz)] = b1;
            sm4[ASZ + brow * 8 + ((cb + 2) ^ swz)] = b2;
            sm4[ASZ + brow * 8 + ((cb + 3) ^ swz)] = b3;
        }
        __syncthreads();

        #pragma unroll
        for (int ks = 0; ks < 2; ks++) {
            int c = ks * 4 + lgrp;
            uint4 a[MF], b[4];
            #pragma unroll
            for (int m = 0; m < MF; m++) {
                int r = wr * (MT / 2) + m * 16 + lrow;
                a[m] = sm4[r * 8 + (c ^ (r & 7))];
            }
            #pragma unroll
            for (int n = 0; n < 4; n++) {
                int r = wc * 64 + n * 16 + lrow;
                b[n] = sm4[ASZ + r * 8 + (c ^ (r & 7))];
            }
            #pragma unroll
            for (int m = 0; m < MF; m++)
                #pragma unroll
                for (int n = 0; n < 4; n++) {
                    if (DT == 0)
                        acc[m][n] = __builtin_amdgcn_mfma_f32_16x16x32_bf16(
                            __builtin_bit_cast(bf16x8, a[m]), __builtin_bit_cast(bf16x8, b[n]), acc[m][n], 0, 0, 0);
                    else
                        acc[m][n] = __builtin_amdgcn_mfma_f32_16x16x32_f16(
                            __builtin_bit_cast(f16x8, a[m]), __builtin_bit_cast(f16x8, b[n]), acc[m][n], 0, 0, 0);
                }
        }
        __syncthreads();
    }

    // epilogue: C/D layout col = lane&15, row = 4*(lane>>4)+reg
    u16* Ts = (u16*)sm4;   // transpose staging (trans blocks), [128][68]
    #pragma unroll
    for (int m = 0; m < MF; m++) {
        #pragma unroll
        for (int n = 0; n < 4; n++) {
            int rbase = row0 + wr * (MT / 2) + m * 16 + lgrp * 4;
            int cc = col0 + wc * 64 + n * 16 + lrow;
            float bv = 0.f;
            if (EPI == EPI_QKV || EPI == EPI_BIAS_RELU)
                bv = bias[cc];
            float vals[4];
            #pragma unroll
            for (int reg = 0; reg < 4; reg++) {
                long r = rbase + reg;
                float v = acc[m][n][reg];
                if (EPI == EPI_QKV) v += bv;
                else if (EPI == EPI_BIAS_RELU) v = fmaxf(v + bv, 0.f);
                else if (EPI == EPI_EDIST) {
                    const float* rnb = bias + (long)z * sBias;
                    float d2 = fmaxf(rnb[r] + rnb[cc] - 2.f * v, 0.f);
                    v = (r == cc) ? 1.f : expf(-sqrtf(d2));
                }
                vals[reg] = v;
                if (OBF) ((u16*)C)[(long)z * sC + r * ldc + cc] = (u16)bf16rne(v);
                else     ((float*)C)[(long)z * sC + r * ldc + cc] = v;
            }
            if (EPI == EPI_EDIST && SWZ == 3 && trans) {
                int cl = cc - col0, rl = rbase - row0;
                uint2 tv;
                tv.x = bfpair(vals[0], vals[1]);
                tv.y = bfpair(vals[2], vals[3]);
                *(uint2*)(Ts + cl * 68 + rl) = tv;
            }
            if (EPI == EPI_QKV && cc >= 512) {
                int b = rbase >> 10;
                uint2 tv;
                tv.x = bfpair(vals[0], vals[1]);
                tv.y = bfpair(vals[2], vals[3]);
                *(uint2*)&vtout[(long)b * NH * NN + (long)(cc - 512) * NN + (rbase & 1023)] = tv;
            }
        }
    }
    if (EPI == EPI_EDIST && SWZ == 3 && trans) {
        __syncthreads();
        int row = tid >> 1, half = tid & 1;
        const u16* src = Ts + row * 68 + half * 32;
        uint2 v0 = *(const uint2*)(src + 0),  v1 = *(const uint2*)(src + 4);
        uint2 v2 = *(const uint2*)(src + 8),  v3 = *(const uint2*)(src + 12);
        uint2 v4 = *(const uint2*)(src + 16), v5 = *(const uint2*)(src + 20);
        uint2 v6 = *(const uint2*)(src + 24), v7 = *(const uint2*)(src + 28);
        uint4* dst = (uint4*)((u16*)C + (long)z * sC + (long)(col0 + row) * ldc + row0 + half * 32);
        uint4 w0 = {v0.x, v0.y, v1.x, v1.y};
        uint4 w1 = {v2.x, v2.y, v3.x, v3.y};
        uint4 w2 = {v4.x, v4.y, v5.x, v5.y};
        uint4 w3 = {v6.x, v6.y, v7.x, v7.y};
        dst[0] = w0; dst[1] = w1; dst[2] = w2; dst[3] = w3;
    }
}

// ==== flash attention + fused ao-proj + residual + LayerNorm1 ================
// grid (32,8) = 256 blocks, 512 thr (8 waves). Block = (batch b, 32 q-rows).
// Cooperative bulk LDS staging (measured best across 6 structures).
__global__ __launch_bounds__(512) void flash_k(
    const u16* __restrict__ qkv,    // [b][1024][768] bf16 (q +0, k +256)
    const u16* __restrict__ vt,     // [b][256][1024] bf16
    const u16* __restrict__ edist,  // [b][1024][1024] bf16
    const u16* __restrict__ aow,    // ao_wt layer: [256 j][256 c] bf16
    const float* __restrict__ aob,
    const float* __restrict__ hres, // h fp32 residual
    const float* __restrict__ g1,
    const float* __restrict__ b1,
    float* __restrict__ xb,
    u16* __restrict__ xbbf,
    float scale)
{
    __shared__ uint4 Ks[128][32];
    __shared__ uint4 Vts[256][16];
    __shared__ __align__(16) u16 Es[32][136];
    __shared__ __align__(16) u16 Ps[32][136];
    __shared__ float rs[32][8];
    __shared__ float lnA[32][8];
    __shared__ float lnB[32][8];

    const int tid = threadIdx.x;
    const int l = tid & 63, w = tid >> 6;
    const int g = l >> 4, lr = l & 15;

    int lid = blockIdx.x + gridDim.x * blockIdx.y;
    const int b = lid & 7;
    const int q0 = (lid >> 3) * 32;

    const u16* qkvb = qkv + (long)b * NN * 768;
    const u16* vtb  = vt + (long)b * NH * NN;
    const u16* eb   = edist + (long)b * NN * NN;

    uint4 qf[2][8];
    #pragma unroll
    for (int m = 0; m < 2; m++)
        #pragma unroll
        for (int ks = 0; ks < 8; ks++)
            qf[m][ks] = *(const uint4*)(qkvb + (long)(q0 + 16 * m + lr) * 768 + 32 * ks + 8 * g);

    f32x4 oacc[2][2];
    #pragma unroll
    for (int m = 0; m < 2; m++)
        #pragma unroll
        for (int nf = 0; nf < 2; nf++) oacc[m][nf] = (f32x4){0.f, 0.f, 0.f, 0.f};
    float rsum[2][4] = {{0.f, 0.f, 0.f, 0.f}, {0.f, 0.f, 0.f, 0.f}};

    for (int n0 = 0; n0 < NN; n0 += 128) {
        #pragma unroll
        for (int i = 0; i < 8; i++) {
            int idx = tid + 512 * i;
            int row = idx >> 5, ch = idx & 31;
            Ks[row][ch ^ (row & 7)] = *(const uint4*)(qkvb + (long)(n0 + row) * 768 + 256 + ch * 8);
        }
        #pragma unroll
        for (int i = 0; i < 8; i++) {
            int idx = tid + 512 * i;
            int c = idx >> 4, ch = idx & 15;
            Vts[c][(ch & 8) | ((ch & 7) ^ (c & 7))] = *(const uint4*)(vtb + (long)c * NN + n0 + ch * 8);
        }
        {
            int r = tid >> 4, ch = tid & 15;
            *(uint4*)&Es[r][ch * 8] = *(const uint4*)(eb + (long)(q0 + r) * NN + n0 + ch * 8);
        }
        __syncthreads();

        f32x4 s[2];
        s[0] = (f32x4){0.f, 0.f, 0.f, 0.f};
        s[1] = (f32x4){0.f, 0.f, 0.f, 0.f};
        const int krow = w * 16 + lr;
        #pragma unroll
        for (int ks = 0; ks < 8; ks++) {
            bf16x8 kf = __builtin_bit_cast(bf16x8, Ks[krow][(4 * ks + g) ^ (krow & 7)]);
            s[0] = __builtin_amdgcn_mfma_f32_16x16x32_bf16(__builtin_bit_cast(bf16x8, qf[0][ks]), kf, s[0], 0, 0, 0);
            s[1] = __builtin_amdgcn_mfma_f32_16x16x32_bf16(__builtin_bit_cast(bf16x8, qf[1][ks]), kf, s[1], 0, 0, 0);
        }
        #pragma unroll
        for (int m = 0; m < 2; m++)
            #pragma unroll
            for (int reg = 0; reg < 4; reg++) {
                int q = 16 * m + 4 * g + reg;
                int kc = w * 16 + lr;
                float p = expf(s[m][reg] * scale * bf2f(Es[q][kc]));
                rsum[m][reg] += p;
                Ps[q][kc] = (u16)bf16rne(p);
            }
        __syncthreads();
        #pragma unroll
        for (int ks = 0; ks < 4; ks++) {
            bf16x8 pa[2], vbf[2];
            #pragma unroll
            for (int m = 0; m < 2; m++)
                pa[m] = __builtin_bit_cast(bf16x8, *(const uint4*)&Ps[16 * m + lr][32 * ks + 8 * g]);
            #pragma unroll
            for (int nf = 0; nf < 2; nf++) {
                int c = w * 32 + nf * 16 + lr;
                int ch = 4 * ks + g;
                vbf[nf] = __builtin_bit_cast(bf16x8, Vts[c][(ch & 8) | ((ch & 7) ^ (c & 7))]);
            }
            #pragma unroll
            for (int m = 0; m < 2; m++)
                #pragma unroll
                for (int nf = 0; nf < 2; nf++)
                    oacc[m][nf] = __builtin_amdgcn_mfma_f32_16x16x32_bf16(pa[m], vbf[nf], oacc[m][nf], 0, 0, 0);
        }
        __syncthreads();
    }

    // rowsum reduction
    #pragma unroll
    for (int m = 0; m < 2; m++)
        #pragma unroll
        for (int reg = 0; reg < 4; reg++) {
            float v = rsum[m][reg];
            v += __shfl_xor(v, 1); v += __shfl_xor(v, 2);
            v += __shfl_xor(v, 4); v += __shfl_xor(v, 8);
            rsum[m][reg] = v;
        }
    if (lr == 0) {
        #pragma unroll
        for (int m = 0; m < 2; m++)
            #pragma unroll
            for (int reg = 0; reg < 4; reg++)
                rs[16 * m + 4 * g + reg][w] = rsum[m][reg];
    }
    __syncthreads();

    // normalized O -> LDS (overlay dead Ks region), bf16
    u16* Os = (u16*)Ks;   // [32][264]
    #pragma unroll
    for (int m = 0; m < 2; m++)
        #pragma unroll
        for (int reg = 0; reg < 4; reg++) {
            int q = 16 * m + 4 * g + reg;
            float t = 0.f;
            #pragma unroll
            for (int j = 0; j < 8; j++) t += rs[q][j];
            float inv = 1.f / t;
            #pragma unroll
            for (int nf = 0; nf < 2; nf++) {
                int c = w * 32 + nf * 16 + lr;
                Os[q * 264 + c] = (u16)bf16rne(oacc[m][nf][reg] * inv);
            }
        }
    __syncthreads();

    // ao GEMM: Os(32x256) @ aow(256j x 256c)^T
    f32x4 aacc[2][2];
    #pragma unroll
    for (int m = 0; m < 2; m++)
        #pragma unroll
        for (int nf = 0; nf < 2; nf++) aacc[m][nf] = (f32x4){0.f, 0.f, 0.f, 0.f};
    #pragma unroll
    for (int kc = 0; kc < 8; kc++) {
        bf16x8 pa[2], wb[2];
        #pragma unroll
        for (int m = 0; m < 2; m++)
            pa[m] = __builtin_bit_cast(bf16x8, *(const uint4*)&Os[(16 * m + lr) * 264 + kc * 32 + 8 * g]);
        #pragma unroll
        for (int nf = 0; nf < 2; nf++)
            wb[nf] = __builtin_bit_cast(bf16x8, *(const uint4*)(aow + (long)(32 * w + 16 * nf + lr) * 256 + kc * 32 + 8 * g));
        #pragma unroll
        for (int m = 0; m < 2; m++)
            #pragma unroll
            for (int nf = 0; nf < 2; nf++)
                aacc[m][nf] = __builtin_amdgcn_mfma_f32_16x16x32_bf16(pa[m], wb[nf], aacc[m][nf], 0, 0, 0);
    }

    // bias + residual
    int j0 = 32 * w + lr, j1 = 32 * w + 16 + lr;
    float aob0 = aob[j0], aob1 = aob[j1];
    float xv[2][2][4];
    #pragma unroll
    for (int m = 0; m < 2; m++)
        #pragma unroll
        for (int reg = 0; reg < 4; reg++) {
            int q = 16 * m + 4 * g + reg;
            long hr = ((long)b * NN + q0 + q) * NH;
            xv[m][0][reg] = aacc[m][0][reg] + aob0 + hres[hr + j0];
            xv[m][1][reg] = aacc[m][1][reg] + aob1 + hres[hr + j1];
        }

    // LN reductions
    #pragma unroll
    for (int m = 0; m < 2; m++)
        #pragma unroll
        for (int reg = 0; reg < 4; reg++) {
            float s = xv[m][0][reg] + xv[m][1][reg];
            float s2 = xv[m][0][reg] * xv[m][0][reg] + xv[m][1][reg] * xv[m][1][reg];
            s  += __shfl_xor(s, 1);  s  += __shfl_xor(s, 2);  s  += __shfl_xor(s, 4);  s  += __shfl_xor(s, 8);
            s2 += __shfl_xor(s2, 1); s2 += __shfl_xor(s2, 2); s2 += __shfl_xor(s2, 4); s2 += __shfl_xor(s2, 8);
            if (lr == 0) {
                int q = 16 * m + 4 * g + reg;
                lnA[q][w] = s;
                lnB[q][w] = s2;
            }
        }
    __syncthreads();

    float g1v0 = g1[j0], g1v1 = g1[j1], b1v0 = b1[j0], b1v1 = b1[j1];
    #pragma unroll
    for (int m = 0; m < 2; m++)
        #pragma unroll
        for (int reg = 0; reg < 4; reg++) {
            int q = 16 * m + 4 * g + reg;
            float S = 0.f, S2 = 0.f;
            #pragma unroll
            for (int j = 0; j < 8; j++) { S += lnA[q][j]; S2 += lnB[q][j]; }
            float mu = S * (1.f / NH);
            float var = S2 * (1.f / NH) - mu * mu;
            float rsd = rsqrtf(var + 1e-5f);
            long hr = ((long)b * NN + q0 + q) * NH;
            float o0 = (xv[m][0][reg] - mu) * rsd * g1v0 + b1v0;
            float o1 = (xv[m][1][reg] - mu) * rsd * g1v1 + b1v1;
            xb[hr + j0] = o0;
            xb[hr + j1] = o1;
            xbbf[hr + j0] = (u16)bf16rne(o0);
            xbbf[hr + j1] = (u16)bf16rne(o1);
        }
}

// ==== fused fc2 + bias + relu + residual + LayerNorm2 ========================
// grid 256 blocks (32 rows x all 256 cols), 256 thr (4 waves), K=1024.
__global__ __launch_bounds__(256) void fc2ln_k(
    const u16* __restrict__ f1,      // [8192][1024] bf16
    const float* __restrict__ resid, // xb fp32
    const u16* __restrict__ w2,      // fc2_wt [256][1024] bf16
    const float* __restrict__ b2,
    const float* __restrict__ g2,
    const float* __restrict__ bb2,
    float* __restrict__ hout,
    u16* __restrict__ hbf)
{
    __shared__ uint4 As[256];    // 32 rows x 8 chunks
    __shared__ uint4 Bs[2048];   // 256 rows x 8 chunks
    __shared__ float lnA[32][4], lnB[32][4];

    const int tid = threadIdx.x;
    const int l = tid & 63, w = tid >> 6;
    const int lrow = l & 15, lgrp = l >> 4;
    const long r0 = (long)blockIdx.x * 32;

    f32x4 acc[2][4];
    #pragma unroll
    for (int m = 0; m < 2; m++)
        #pragma unroll
        for (int n = 0; n < 4; n++) acc[m][n] = (f32x4){0.f, 0.f, 0.f, 0.f};

    for (int k0 = 0; k0 < 1024; k0 += 64) {
        {
            int row = tid >> 3, ch = tid & 7;
            As[row * 8 + (ch ^ (row & 7))] = *(const uint4*)(f1 + (r0 + row) * 1024 + k0 + ch * 8);
        }
        #pragma unroll
        for (int i = 0; i < 8; i++) {
            int idx = tid + 256 * i;
            int row = idx >> 3, ch = idx & 7;
            Bs[row * 8 + (ch ^ (row & 7))] = *(const uint4*)(w2 + (long)row * 1024 + k0 + ch * 8);
        }
        __syncthreads();
        #pragma unroll
        for (int ks = 0; ks < 2; ks++) {
            int c = ks * 4 + lgrp;
            uint4 a[2], b[4];
            #pragma unroll
            for (int m = 0; m < 2; m++) {
                int r = m * 16 + lrow;
                a[m] = As[r * 8 + (c ^ (r & 7))];
            }
            #pragma unroll
            for (int n = 0; n < 4; n++) {
                int r = 64 * w + n * 16 + lrow;
                b[n] = Bs[r * 8 + (c ^ (r & 7))];
            }
            #pragma unroll
            for (int m = 0; m < 2; m++)
                #pragma unroll
                for (int n = 0; n < 4; n++)
                    acc[m][n] = __builtin_amdgcn_mfma_f32_16x16x32_bf16(
                        __builtin_bit_cast(bf16x8, a[m]), __builtin_bit_cast(bf16x8, b[n]), acc[m][n], 0, 0, 0);
        }
        __syncthreads();
    }

    // epilogue: row rr = 16m+4*lgrp+reg (local), col cc = 64w+16n+lrow
    float xv[2][4][4];
    #pragma unroll
    for (int m = 0; m < 2; m++)
        #pragma unroll
        for (int n = 0; n < 4; n++) {
            int cc = 64 * w + 16 * n + lrow;
            float bv = b2[cc];
            #pragma unroll
            for (int reg = 0; reg < 4; reg++) {
                int rr = 16 * m + 4 * lgrp + reg;
                xv[m][n][reg] = fmaxf(acc[m][n][reg] + bv, 0.f) + resid[(r0 + rr) * 256 + cc];
            }
        }

    // LN partials: per row, sum over this wave's 64 cols
    #pragma unroll
    for (int m = 0; m < 2; m++)
        #pragma unroll
        for (int reg = 0; reg < 4; reg++) {
            float s = 0.f, s2 = 0.f;
            #pragma unroll
            for (int n = 0; n < 4; n++) {
                s += xv[m][n][reg];
                s2 += xv[m][n][reg] * xv[m][n][reg];
            }
            s  += __shfl_xor(s, 1);  s  += __shfl_xor(s, 2);  s  += __shfl_xor(s, 4);  s  += __shfl_xor(s, 8);
            s2 += __shfl_xor(s2, 1); s2 += __shfl_xor(s2, 2); s2 += __shfl_xor(s2, 4); s2 += __shfl_xor(s2, 8);
            if (lrow == 0) {
                int rr = 16 * m + 4 * lgrp + reg;
                lnA[rr][w] = s;
                lnB[rr][w] = s2;
            }
        }
    __syncthreads();

    #pragma unroll
    for (int m = 0; m < 2; m++)
        #pragma unroll
        for (int reg = 0; reg < 4; reg++) {
            int rr = 16 * m + 4 * lgrp + reg;
            float S = lnA[rr][0] + lnA[rr][1] + lnA[rr][2] + lnA[rr][3];
            float S2 = lnB[rr][0] + lnB[rr][1] + lnB[rr][2] + lnB[rr][3];
            float mu = S * (1.f / NH);
            float var = S2 * (1.f / NH) - mu * mu;
            float rsd = rsqrtf(var + 1e-5f);
            #pragma unroll
            for (int n = 0; n < 4; n++) {
                int cc = 64 * w + 16 * n + lrow;
                float o = (xv[m][n][reg] - mu) * rsd * g2[cc] + bb2[cc];
                hout[(r0 + rr) * 256 + cc] = o;
                hbf[(r0 + rr) * 256 + cc] = (u16)bf16rne(o);
            }
        }
}

__global__ __launch_bounds__(256) void base_k(const int* __restrict__ t,
                                              const float* __restrict__ w_time,
                                              const float* __restrict__ b_time,
                                              const float* __restrict__ w_in,
                                              const float* __restrict__ b_in,
                                              float* __restrict__ base) {
    int b = blockIdx.x, j = threadIdx.x;
    __shared__ float te[256];
    float tf = (float)t[b] / 200.0f;
    te[j] = fmaxf(tf * w_time[j] + b_time[j], 0.f);
    __syncthreads();
    float acc = b_in[j];
    for (int k = 0; k < 256; k++) acc = fmaf(te[k], w_in[(3 + k) * 256 + j], acc);
    base[b * 256 + j] = acc;
}

__global__ __launch_bounds__(256) void hinit_k(const float* __restrict__ x,
                                               const float* __restrict__ w_in,
                                               const float* __restrict__ base,
                                               float* __restrict__ h,
                                               u16* __restrict__ hbf,
                                               float* __restrict__ h3) {
    long row = blockIdx.x;
    int b = (int)(row >> 10);
    int j = threadIdx.x;
    float x0 = x[row * 3 + 0], x1 = x[row * 3 + 1], x2 = x[row * 3 + 2];
    float v = base[b * 256 + j];
    v = fmaf(x0, w_in[j], v);
    v = fmaf(x1, w_in[256 + j], v);
    v = fmaf(x2, w_in[512 + j], v);
    v = fmaxf(v, 0.f);
    h[row * 256 + j] = v;
    hbf[row * 256 + j] = (u16)bf16rne(v);
    if (j < 3) h3[row * 3 + j] = v;
}

// geo row -> fp16 bits, rn = sum of represented^2
__global__ __launch_bounds__(256) void geo_k(const float* __restrict__ h3,
                                             u16* __restrict__ gf,
                                             float* __restrict__ rn) {
    int bi = blockIdx.x;
    int b = bi >> 10, i = bi & 1023;
    const float* hb = h3 + (long)b * NN * 3;
    float ax = hb[i * 3 + 0], ay = hb[i * 3 + 1], az = hb[i * 3 + 2];
    u16* grow = gf + (long)bi * 1024;
    float accs = 0.f;
    #pragma unroll
    for (int j0 = 0; j0 < NN; j0 += 256) {
        int j = j0 + threadIdx.x;
        float dx = hb[j * 3 + 0] - ax, dy = hb[j * 3 + 1] - ay, dz = hb[j * 3 + 2] - az;
        float d2 = dx * dx + dy * dy + dz * dz;
        float d = (d2 > 0.f) ? sqrtf(d2) : 0.f;
        _Float16 hf = (_Float16)d;
        float rep = (float)hf;
        grow[j] = __builtin_bit_cast(u16, hf);
        accs += rep * rep;
    }
    float tot = blockSum256(accs);
    if (threadIdx.x == 0) rn[bi] = tot;
}

__global__ __launch_bounds__(256) void wtrans_k(const float* __restrict__ qkv_w,
                                                const float* __restrict__ ao_w,
                                                const float* __restrict__ fc1_w,
                                                const float* __restrict__ fc2_w,
                                                u16* __restrict__ qkv_wt,
                                                u16* __restrict__ ao_wt,
                                                u16* __restrict__ fc1_wt,
                                                u16* __restrict__ fc2_wt) {
    int type = blockIdx.z, lyr = blockIdx.y;
    int R, Cc;
    const float* src;
    u16* dst;
    if (type == 0) { R = 256; Cc = 768;  src = qkv_w + (long)lyr * R * Cc; dst = qkv_wt + (long)lyr * R * Cc; }
    else if (type == 1) { R = 256; Cc = 256; src = ao_w + (long)lyr * R * Cc; dst = ao_wt + (long)lyr * R * Cc; }
    else if (type == 2) { R = 256; Cc = 1024; src = fc1_w + (long)lyr * R * Cc; dst = fc1_wt + (long)lyr * R * Cc; }
    else { R = 1024; Cc = 256; src = fc2_w + (long)lyr * R * Cc; dst = fc2_wt + (long)lyr * R * Cc; }
    int tC = Cc >> 5, tR = R >> 5;
    int tile = blockIdx.x;
    if (tile >= tC * tR) return;
    int c0 = (tile % tC) << 5, r0 = (tile / tC) << 5;
    __shared__ float tf[32][33];
    int tx = threadIdx.x & 31, ty = threadIdx.x >> 5;
    #pragma unroll
    for (int i = 0; i < 4; i++) {
        int r = ty + 8 * i;
        tf[r][tx] = src[(long)(r0 + r) * Cc + c0 + tx];
    }
    __syncthreads();
    #pragma unroll
    for (int i = 0; i < 4; i++) {
        int c = ty + 8 * i;
        dst[(long)(c0 + c) * R + r0 + tx] = (u16)bf16rne(tf[tx][c]);
    }
}

__global__ __launch_bounds__(256) void out_k(const float* __restrict__ h,
                                             const float* __restrict__ w_out,
                                             const float* __restrict__ b_out,
                                             float* __restrict__ out) {
    long row = blockIdx.x;
    int wid = threadIdx.x >> 6, lane = threadIdx.x & 63;
    if (wid < 3) {
        float acc = 0.f;
        for (int k = lane; k < 256; k += 64) acc = fmaf(h[row * 256 + k], w_out[k * 3 + wid], acc);
        #pragma unroll
        for (int o = 32; o; o >>= 1) acc += __shfl_down(acc, o, 64);
        if (lane == 0) out[row * 3 + wid] = acc + b_out[wid];
    }
}

extern "C" void kernel_launch(void* const* d_in, const int* in_sizes, int n_in,
                              void* d_out, int out_size, void* d_ws, size_t ws_size,
                              hipStream_t stream) {
    const float* x      = (const float*)d_in[0];
    const int*   t      = (const int*)  d_in[1];
    const float* w_time = (const float*)d_in[3];
    const float* b_time = (const float*)d_in[4];
    const float* w_in   = (const float*)d_in[5];
    const float* b_in   = (const float*)d_in[6];
    const float* w_out  = (const float*)d_in[7];
    const float* b_out  = (const float*)d_in[8];
    const float* qkv_w  = (const float*)d_in[9];
    const float* qkv_b  = (const float*)d_in[10];
    const float* ao_w   = (const float*)d_in[11];
    const float* ao_b   = (const float*)d_in[12];
    const float* fc1_w  = (const float*)d_in[13];
    const float* fc1_b  = (const float*)d_in[14];
    const float* fc2_w  = (const float*)d_in[15];
    const float* fc2_b  = (const float*)d_in[16];
    const float* ln1_g  = (const float*)d_in[17];
    const float* ln1_b  = (const float*)d_in[18];
    const float* ln2_g  = (const float*)d_in[19];
    const float* ln2_b  = (const float*)d_in[20];
    float* out = (float*)d_out;

    char* W = (char*)d_ws;
    float* h     = (float*)(W);                          // 8 MB
    float* xb    = (float*)(W + (8ul << 20));            // 8 MB
    u16*   hbf   = (u16*)  (W + (16ul << 20));           // 4 MB
    u16*   xbbf  = (u16*)  (W + (20ul << 20));           // 4 MB
    u16*   vt    = (u16*)  (W + (24ul << 20));           // 4 MB
    u16*   f1    = (u16*)  (W + (28ul << 20));           // 16 MB
    u16*   qkvb  = (u16*)  (W + (44ul << 20));           // 12 MB
    u16*   edist = (u16*)  (W + (56ul << 20));           // 16 MB
    u16*   gf    = (u16*)  (W + (72ul << 20));           // 16 MB (fp16 geo)
    u16*   wts   = (u16*)  (W + (88ul << 20));           // 4.5 MB
    u16* qkv_wt = wts;                // 3 * 196608
    u16* ao_wt  = wts + 589824;       // 3 * 65536
    u16* fc1_wt = wts + 786432;       // 3 * 262144
    u16* fc2_wt = wts + 1572864;      // 3 * 262144
    float* base = (float*)(W + (94ul << 20));
    float* rn   = base + 2048;
    float* h3   = rn + 8192;

    const float scale = 1.0f / 16.0f;

    base_k<<<NB, 256, 0, stream>>>(t, w_time, b_time, w_in, b_in, base);
    hinit_k<<<NB * NN, 256, 0, stream>>>(x, w_in, base, h, hbf, h3);
    geo_k<<<NB * NN, 256, 0, stream>>>(h3, gf, rn);
    wtrans_k<<<dim3(256, NL, 4), 256, 0, stream>>>(qkv_w, ao_w, fc1_w, fc2_w,
                                                   qkv_wt, ao_wt, fc1_wt, fc2_wt);
    // edist: fp16 Gram, K=1024, symmetric 64-row triangular tiles (576 blocks)
    gemm_mfma<EPI_EDIST, 1, true, 3, 64><<<dim3(72, 1, 8), 256, 0, stream>>>(
        gf, 1024, (long)NN * 1024, gf, 1024, (long)NN * 1024,
        edist, NN, (long)NN * NN, 1024, rn, NN, nullptr);

    for (int l = 0; l < NL; ++l) {
        // qkv (bf16 out, MT=64 -> 768 blocks) + fused v-transpose into vt
        gemm_mfma<EPI_QKV, 0, true, 2, 64><<<dim3(6, 128, 1), 256, 0, stream>>>(
            hbf, NH, 0, qkv_wt + (long)l * 196608, NH, 0, qkvb, 768, 0,
            NH, qkv_b + l * 768, 0, vt);
        // fused attention + ao-proj + residual + LN1 -> xb / xbbf
        flash_k<<<dim3(32, 8), 512, 0, stream>>>(
            qkvb, vt, edist, ao_wt + (long)l * 65536, ao_b + l * NH,
            h, ln1_g + l * NH, ln1_b + l * NH, xb, xbbf, scale);
        // f1 = relu(xb @ fc1_wt^T + b)  (bf16 out)
        gemm_mfma<EPI_BIAS_RELU, 0, true, 2, 128><<<dim3(8, 64, 1), 256, 0, stream>>>(
            xbbf, NH, 0, fc1_wt + (long)l * 262144, NH, 0, f1, 1024, 0,
            NH, fc1_b + l * 1024, 0, nullptr);
        // fused fc2 + bias + relu + residual + LN2 -> h / hbf
        fc2ln_k<<<256, 256, 0, stream>>>(
            f1, xb, fc2_wt + (long)l * 262144, fc2_b + l * NH,
            ln2_g + l * NH, ln2_b + l * NH, h, hbf);
    }
    out_k<<<NB * NN, 256, 0, stream>>>(h, w_out, b_out, out);
}